// Round 3
// baseline (11391.102 us; speedup 1.0000x reference)
//
#include <hip/hip_runtime.h>
#include <hip/hip_bf16.h>
#include <stdint.h>

#define BATCH 4096
#define TT    80
#define EMB   100
#define UNITS 512
#define N4    2048
#define K0P   128

typedef unsigned short ushort;
typedef unsigned char uchar;
typedef __bf16 bf16x8 __attribute__((ext_vector_type(8)));
typedef float f32x4 __attribute__((ext_vector_type(4)));

// ---------------- threefry2x32 (JAX partitionable mode, verified r1) ------
__device__ __forceinline__ uint32_t rotl32(uint32_t x, uint32_t r) {
  return (x << r) | (x >> (32u - r));
}
__device__ __forceinline__ void tf_round4(uint32_t& x0, uint32_t& x1,
                                          int r0, int r1, int r2, int r3) {
  x0 += x1; x1 = rotl32(x1, r0); x1 ^= x0;
  x0 += x1; x1 = rotl32(x1, r1); x1 ^= x0;
  x0 += x1; x1 = rotl32(x1, r2); x1 ^= x0;
  x0 += x1; x1 = rotl32(x1, r3); x1 ^= x0;
}
__device__ __forceinline__ void tf2x32(uint32_t k0, uint32_t k1,
                                       uint32_t x0, uint32_t x1,
                                       uint32_t& y0, uint32_t& y1) {
  uint32_t k2 = k0 ^ k1 ^ 0x1BD11BDAu;
  x0 += k0; x1 += k1;
  tf_round4(x0, x1, 13, 15, 26, 6);  x0 += k1; x1 += k2 + 1u;
  tf_round4(x0, x1, 17, 29, 16, 24); x0 += k2; x1 += k0 + 2u;
  tf_round4(x0, x1, 13, 15, 26, 6);  x0 += k0; x1 += k1 + 3u;
  tf_round4(x0, x1, 17, 29, 16, 24); x0 += k1; x1 += k2 + 4u;
  tf_round4(x0, x1, 13, 15, 26, 6);  x0 += k2; x1 += k0 + 5u;
  y0 = x0; y1 = x1;
}
__device__ __forceinline__ int keepbit(uint32_t u) {
  float f = __uint_as_float((u >> 9) | 0x3F800000u) - 1.0f;
  return f < 0.8f ? 1 : 0;
}
__device__ __forceinline__ ushort f2bf(float f) {
  uint32_t u = __float_as_uint(f);
  uint32_t r = (u + 0x7FFFu + ((u >> 16) & 1u)) >> 16;
  return (ushort)r;
}
__device__ __forceinline__ float bf2f(ushort u) {
  return __uint_as_float(((uint32_t)u) << 16);
}

__global__ __launch_bounds__(256) void masks_kernel(uchar* __restrict__ m0p,
                                                    uchar* __restrict__ m1p) {
  uint32_t k0a, k0b, k1a, k1b;
  tf2x32(0u, 42u, 0u, 0u, k0a, k0b);
  tf2x32(0u, 42u, 0u, 1u, k1a, k1b);
  const int n0 = BATCH * EMB;
  const int n1 = BATCH * UNITS;
  const int total = n0 + n1;
  for (int i = blockIdx.x * blockDim.x + threadIdx.x; i < total;
       i += gridDim.x * blockDim.x) {
    if (i < n0) {
      uchar byte = 0;
#pragma unroll
      for (int g = 0; g < 4; g++) {
        uint32_t y0, y1;
        tf2x32(k0a, k0b, 0u, (uint32_t)(g * n0 + i), y0, y1);
        byte |= keepbit(y0 ^ y1) << g;
      }
      m0p[i] = byte;
    } else {
      int j = i - n0;
      uchar byte = 0;
#pragma unroll
      for (int g = 0; g < 4; g++) {
        uint32_t y0, y1;
        tf2x32(k1a, k1b, 0u, (uint32_t)(g * n1 + j), y0, y1);
        byte |= keepbit(y0 ^ y1) << g;
      }
      m1p[j] = byte;
    }
  }
}

// weight convert+transpose: src[K][2048] f32 -> dst[2048][Kpad] bf16
__global__ __launch_bounds__(256) void convT(const float* __restrict__ src,
                                             ushort* __restrict__ dst,
                                             int Ksrc, int Kpad) {
  __shared__ float t[32][33];
  const int n0 = blockIdx.x * 32, kk0 = blockIdx.y * 32;
  const int tx = threadIdx.x & 31, ty = threadIdx.x >> 5;
#pragma unroll
  for (int r = ty; r < 32; r += 8) {
    const int k = kk0 + r;
    t[r][tx] = (k < Ksrc) ? src[(size_t)k * N4 + n0 + tx] : 0.f;
  }
  __syncthreads();
#pragma unroll
  for (int r = ty; r < 32; r += 8)
    dst[(size_t)(n0 + r) * Kpad + kk0 + tx] = f2bf(t[tx][r]);
}

// Xm0 prep: per-gate masked embed, bf16, [4][4096][128]
__device__ __forceinline__ void xm0_prep_one(int i, int t,
                                             const int* __restrict__ inputs,
                                             const float* __restrict__ embed,
                                             const uchar* __restrict__ m0p,
                                             ushort* __restrict__ Xm0) {
  const int k = i & 127;
  const int b = (i >> 7) & 4095;
  const int g = i >> 19;
  float v = 0.f;
  if (k < EMB) {
    const int idx = inputs[b * TT + t];
    const float e = embed[(size_t)idx * EMB + k];
    v = ((m0p[b * EMB + k] >> g) & 1) ? e * 1.25f : 0.f;
  }
  Xm0[((size_t)g << 19) + (b << 7) + k] = f2bf(v);
}

__global__ __launch_bounds__(256) void prep_x2(const int* __restrict__ inputs,
                                               const float* __restrict__ embed,
                                               const uchar* __restrict__ m0p,
                                               ushort* __restrict__ Xm0_0,
                                               ushort* __restrict__ Xm0_1) {
  const int i = blockIdx.x * blockDim.x + threadIdx.x;
  if (i < (1 << 21)) xm0_prep_one(i, 0, inputs, embed, m0p, Xm0_0);
  else xm0_prep_one(i - (1 << 21), 1, inputs, embed, m0p, Xm0_1);
}

__device__ __forceinline__ void gload16(const void* g, void* l) {
  __builtin_amdgcn_global_load_lds(
      (const __attribute__((address_space(1))) unsigned int*)g,
      (__attribute__((address_space(3))) unsigned int*)l, 16, 0, 0);
}

// ---------------- fused cell: z = Am_g@WT^T + h_prev@UT^T + b -> gates ----
// Block: 128 rows x (4 gates x 64 h) via two 32-h subtiles. 4 waves, each
// 32 rows x all cols. acc[s][fi][fj]: fj = g*2+hf, col = g*32+hf*16+fr.
__device__ __forceinline__ void cell_part(
    int bid, int tid,
    const ushort* __restrict__ Am, size_t gstride, int Km,
    const ushort* __restrict__ Ash,   // h_prev [4096][512] bf16
    const ushort* __restrict__ WT,    // [2048][Km]
    const ushort* __restrict__ UT,    // [2048][512]
    const float* __restrict__ bias,
    float* __restrict__ c,
    ushort* __restrict__ h_wr,
    ushort* __restrict__ H0m_wr,      // nullptr for layer1
    const uchar* __restrict__ m1p,
    ushort* smem) {
  const int w = tid >> 6, l = tid & 63;
  const int fr = l & 15, kq = l >> 4;
  const int srow = l >> 2;            // 0..15 staging row
  const int schunk = (l & 3) * 8;     // 8-elem k-chunk
  // XCD-chunked swizzle over 256 blocks -> (mblk 0..31, nblk 0..7)
  const int cid = (bid & 7) * 32 + (bid >> 3);
  const int bm0 = (cid >> 3) * 128;
  const int bh0 = (cid & 7) * 64;
  ushort* Bs = smem + 16384;

  f32x4 acc[2][2][8] = {};

  // ---- masked segment: per-gate A ----
  for (int k0 = 0; k0 < Km; k0 += 32) {
#pragma unroll
    for (int g = 0; g < 4; g++)
#pragma unroll
      for (int c2 = 0; c2 < 2; c2++) {
        const int row = w * 32 + c2 * 16;
        gload16(Am + (size_t)g * gstride + (size_t)(bm0 + row + srow) * Km +
                    k0 + schunk,
                smem + (g * 128 + row) * 32);
      }
#pragma unroll
    for (int s = 0; s < 2; s++)
#pragma unroll
      for (int c2 = 0; c2 < 2; c2++) {
        const int jb = w * 32 + c2 * 16;
        const int j = jb + srow;
        gload16(WT + (size_t)((j >> 5) * 512 + bh0 + s * 32 + (j & 31)) * Km +
                    k0 + schunk,
                Bs + s * 4096 + jb * 32);
      }
    __syncthreads();
    bf16x8 bfr[2][8], am[4][2];
#pragma unroll
    for (int s = 0; s < 2; s++)
#pragma unroll
      for (int fj = 0; fj < 8; fj++)
        bfr[s][fj] = *(const bf16x8*)&Bs[s * 4096 + (fj * 16 + fr) * 32 + kq * 8];
#pragma unroll
    for (int g = 0; g < 4; g++)
#pragma unroll
      for (int fi = 0; fi < 2; fi++)
        am[g][fi] =
            *(const bf16x8*)&smem[(g * 128 + w * 32 + fi * 16 + fr) * 32 + kq * 8];
#pragma unroll
    for (int s = 0; s < 2; s++)
#pragma unroll
      for (int fi = 0; fi < 2; fi++)
#pragma unroll
        for (int fj = 0; fj < 8; fj++)
          acc[s][fi][fj] = __builtin_amdgcn_mfma_f32_16x16x32_bf16(
              am[fj >> 1][fi], bfr[s][fj], acc[s][fi][fj], 0, 0, 0);
    __syncthreads();
  }

  // ---- shared segment: h_prev @ U^T, K=512 ----
  for (int k0 = 0; k0 < 512; k0 += 32) {
#pragma unroll
    for (int c2 = 0; c2 < 2; c2++) {
      const int row = w * 32 + c2 * 16;
      gload16(Ash + (size_t)(bm0 + row + srow) * 512 + k0 + schunk,
              smem + row * 32);
    }
#pragma unroll
    for (int s = 0; s < 2; s++)
#pragma unroll
      for (int c2 = 0; c2 < 2; c2++) {
        const int jb = w * 32 + c2 * 16;
        const int j = jb + srow;
        gload16(UT + (size_t)((j >> 5) * 512 + bh0 + s * 32 + (j & 31)) * 512 +
                    k0 + schunk,
                Bs + s * 4096 + jb * 32);
      }
    __syncthreads();
    bf16x8 bfr[2][8], a2[2];
#pragma unroll
    for (int s = 0; s < 2; s++)
#pragma unroll
      for (int fj = 0; fj < 8; fj++)
        bfr[s][fj] = *(const bf16x8*)&Bs[s * 4096 + (fj * 16 + fr) * 32 + kq * 8];
#pragma unroll
    for (int fi = 0; fi < 2; fi++)
      a2[fi] = *(const bf16x8*)&smem[(w * 32 + fi * 16 + fr) * 32 + kq * 8];
#pragma unroll
    for (int s = 0; s < 2; s++)
#pragma unroll
      for (int fi = 0; fi < 2; fi++)
#pragma unroll
        for (int fj = 0; fj < 8; fj++)
          acc[s][fi][fj] = __builtin_amdgcn_mfma_f32_16x16x32_bf16(
              a2[fi], bfr[s][fj], acc[s][fi][fj], 0, 0, 0);
    __syncthreads();
  }

  // ---- fused LSTM-gate epilogue ----
#pragma unroll
  for (int s = 0; s < 2; s++) {
#pragma unroll
    for (int hf = 0; hf < 2; hf++) {
      const int h = bh0 + s * 32 + hf * 16 + fr;
      const float bvi = bias[h];
      const float bvf = bias[512 + h];
      const float bvg = bias[1024 + h];
      const float bvo = bias[1536 + h];
#pragma unroll
      for (int fi = 0; fi < 2; fi++) {
#pragma unroll
        for (int jj = 0; jj < 4; jj++) {
          const int r = bm0 + w * 32 + fi * 16 + kq * 4 + jj;
          const float zi = acc[s][fi][0 + hf][jj] + bvi;
          const float zf = acc[s][fi][2 + hf][jj] + bvf;
          const float zg = acc[s][fi][4 + hf][jj] + bvg;
          const float zo = acc[s][fi][6 + hf][jj] + bvo;
          const float iv = 1.f / (1.f + __expf(-zi));
          const float fv = 1.f / (1.f + __expf(-zf));
          const float gv = tanhf(zg);
          const float ov = 1.f / (1.f + __expf(-zo));
          const size_t ci = (size_t)r * 512 + h;
          const float cn = fv * c[ci] + iv * gv;
          c[ci] = cn;
          const float hn = ov * tanhf(cn);
          h_wr[ci] = f2bf(hn);
          if (H0m_wr) {
            const uchar mb = m1p[ci];
            const float hm = hn * 1.25f;
#pragma unroll
            for (int g = 0; g < 4; g++)
              H0m_wr[((size_t)g << 21) + ci] = f2bf((mb >> g) & 1 ? hm : 0.f);
          }
        }
      }
    }
  }
}

__global__ __launch_bounds__(256) void fused_step(
    int t, int nl1, int nl0, int naux,
    // layer1 (t):
    const ushort* H0m_rd, const ushort* h1_rd, ushort* h1_wr, float* c1,
    const ushort* W1T, const ushort* U1T, const float* b1,
    // layer0 (t+1):
    const ushort* Xm0_rd, const ushort* h0_rd, ushort* h0_wr, ushort* H0m_wr,
    float* c0, const ushort* W0T, const ushort* U0T, const float* b0,
    const uchar* m1p,
    // aux (Xm0 for t+2):
    const int* inputs, const float* embed, const uchar* m0p, ushort* Xm0_wr) {
  __shared__ __align__(16) ushort smem[24576];
  const int bid = blockIdx.x, tid = threadIdx.x;
  if (bid < nl1) {
    cell_part(bid, tid, H0m_rd, (size_t)1 << 21, 512, h1_rd, W1T, U1T, b1, c1,
              h1_wr, nullptr, nullptr, smem);
  } else if (bid < nl1 + nl0) {
    cell_part(bid - nl1, tid, Xm0_rd, (size_t)1 << 19, K0P, h0_rd, W0T, U0T, b0,
              c0, h0_wr, H0m_wr, m1p, smem);
  } else {
    const int i0 = (bid - nl1 - nl0) * 256 + tid;
    const int stride = naux * 256;
    for (int i = i0; i < (1 << 21); i += stride)
      xm0_prep_one(i, t + 2, inputs, embed, m0p, Xm0_wr);
  }
}

__global__ __launch_bounds__(256) void out_kernel(const ushort* __restrict__ h1b,
                                                  const float* __restrict__ Wout,
                                                  const float* __restrict__ bout,
                                                  float* __restrict__ out) {
  const int wid = (blockIdx.x * blockDim.x + threadIdx.x) >> 6;
  const int lane = threadIdx.x & 63;
  if (wid >= BATCH) return;
  const ushort* hr = h1b + (size_t)wid * UNITS;
  float s = 0.f;
#pragma unroll
  for (int j = 0; j < UNITS; j += 64) s += bf2f(hr[j + lane]) * Wout[j + lane];
  for (int off = 32; off; off >>= 1) s += __shfl_down(s, off, 64);
  if (lane == 0) out[wid] = 1.f / (1.f + __expf(-(s + bout[0])));
}

// --------------------------------------------------------------------------
extern "C" void kernel_launch(void* const* d_in, const int* in_sizes, int n_in,
                              void* d_out, int out_size, void* d_ws, size_t ws_size,
                              hipStream_t stream) {
  const int* inputs = (const int*)d_in[0];
  const float* embed = (const float*)d_in[1];
  const float* W0 = (const float*)d_in[2];
  const float* U0 = (const float*)d_in[3];
  const float* b0 = (const float*)d_in[4];
  const float* W1 = (const float*)d_in[5];
  const float* U1 = (const float*)d_in[6];
  const float* b1 = (const float*)d_in[7];
  const float* Wout = (const float*)d_in[8];
  const float* bout = (const float*)d_in[9];
  float* out = (float*)d_out;

  char* ws = (char*)d_ws;
  float* c0     = (float*)(ws + 0);            //  8 MB
  float* c1     = (float*)(ws + 8388608);      //  8 MB
  ushort* h0b1  = (ushort*)(ws + 16777216);    //  4 MB (zero-init)
  ushort* h1b1  = (ushort*)(ws + 20971520);    //  4 MB (zero-init)
  ushort* h0b0  = (ushort*)(ws + 25165824);    //  4 MB
  ushort* h1b0  = (ushort*)(ws + 29360128);    //  4 MB
  ushort* H0m0  = (ushort*)(ws + 33554432);    // 16 MB
  ushort* H0m1  = (ushort*)(ws + 50331648);    // 16 MB
  ushort* Xm00  = (ushort*)(ws + 67108864);    //  4 MB
  ushort* Xm01  = (ushort*)(ws + 71303168);    //  4 MB
  ushort* W0T   = (ushort*)(ws + 75497472);    //  512 KB
  ushort* U0T   = (ushort*)(ws + 76021760);    //  2 MB
  ushort* W1T   = (ushort*)(ws + 78118912);    //  2 MB
  ushort* U1T   = (ushort*)(ws + 80216064);    //  2 MB
  uchar* m0p    = (uchar*)(ws + 82313216);     //  400 KB
  uchar* m1p    = (uchar*)(ws + 82722816);     //  2 MB

  ushort* h0b[2] = {h0b0, h0b1};
  ushort* h1b[2] = {h1b0, h1b1};
  ushort* H0m[2] = {H0m0, H0m1};
  ushort* Xm0[2] = {Xm00, Xm01};

  // zero c0, c1, h0b[1], h1b[1] (contiguous 24 MB)
  hipMemsetAsync(ws, 0, 25165824, stream);

  masks_kernel<<<2048, 256, 0, stream>>>(m0p, m1p);
  {
    dim3 g0(N4 / 32, K0P / 32);
    convT<<<g0, 256, 0, stream>>>(W0, W0T, EMB, K0P);
    dim3 g1(N4 / 32, UNITS / 32);
    convT<<<g1, 256, 0, stream>>>(U0, U0T, UNITS, UNITS);
    convT<<<g1, 256, 0, stream>>>(W1, W1T, UNITS, UNITS);
    convT<<<g1, 256, 0, stream>>>(U1, U1T, UNITS, UNITS);
  }
  prep_x2<<<(2 << 21) / 256, 256, 0, stream>>>(inputs, embed, m0p, Xm00, Xm01);

  // prologue: layer0 t=0 only (reads Xm0[0], h0b[1]=0; writes h0b[0], H0m[0])
  fused_step<<<256, 256, 0, stream>>>(
      -1, 0, 256, 0, H0m0, h1b1, h1b0, c1, W1T, U1T, b1, Xm00, h0b1, h0b0,
      H0m0, c0, W0T, U0T, b0, m1p, inputs, embed, m0p, Xm00);

  for (int k = 0; k < TT; k++) {
    const int pt = k & 1, pn = pt ^ 1;
    const int nl0 = (k < TT - 1) ? 256 : 0;
    const int naux = (k < TT - 2) ? 64 : 0;
    fused_step<<<256 + nl0 + naux, 256, 0, stream>>>(
        k, 256, nl0, naux,
        H0m[pt], h1b[pn], h1b[pt], c1, W1T, U1T, b1,
        Xm0[pn], h0b[pt], h0b[pn], H0m[pn], c0, W0T, U0T, b0, m1p,
        inputs, embed, m0p, Xm0[pt]);
  }

  out_kernel<<<BATCH * 64 / 256, 256, 0, stream>>>(h1b[1], Wout, bout, out);
}

// Round 4
// 6276.048 us; speedup vs baseline: 1.8150x; 1.8150x over previous
//
#include <hip/hip_runtime.h>
#include <hip/hip_bf16.h>
#include <stdint.h>

#define BATCH 4096
#define TT    80
#define EMB   100
#define UNITS 512
#define K0P   128

typedef unsigned short ushort;
typedef unsigned char uchar;
typedef __bf16 bf16x8 __attribute__((ext_vector_type(8)));
typedef float f32x4 __attribute__((ext_vector_type(4)));
typedef uint32_t u32x4 __attribute__((ext_vector_type(4)));

// ---------------- threefry2x32 (JAX partitionable mode, verified r1) ------
__device__ __forceinline__ uint32_t rotl32(uint32_t x, uint32_t r) {
  return (x << r) | (x >> (32u - r));
}
__device__ __forceinline__ void tf_round4(uint32_t& x0, uint32_t& x1,
                                          int r0, int r1, int r2, int r3) {
  x0 += x1; x1 = rotl32(x1, r0); x1 ^= x0;
  x0 += x1; x1 = rotl32(x1, r1); x1 ^= x0;
  x0 += x1; x1 = rotl32(x1, r2); x1 ^= x0;
  x0 += x1; x1 = rotl32(x1, r3); x1 ^= x0;
}
__device__ __forceinline__ void tf2x32(uint32_t k0, uint32_t k1,
                                       uint32_t x0, uint32_t x1,
                                       uint32_t& y0, uint32_t& y1) {
  uint32_t k2 = k0 ^ k1 ^ 0x1BD11BDAu;
  x0 += k0; x1 += k1;
  tf_round4(x0, x1, 13, 15, 26, 6);  x0 += k1; x1 += k2 + 1u;
  tf_round4(x0, x1, 17, 29, 16, 24); x0 += k2; x1 += k0 + 2u;
  tf_round4(x0, x1, 13, 15, 26, 6);  x0 += k0; x1 += k1 + 3u;
  tf_round4(x0, x1, 17, 29, 16, 24); x0 += k1; x1 += k2 + 4u;
  tf_round4(x0, x1, 13, 15, 26, 6);  x0 += k2; x1 += k0 + 5u;
  y0 = x0; y1 = x1;
}
__device__ __forceinline__ int keepbit(uint32_t u) {
  float f = __uint_as_float((u >> 9) | 0x3F800000u) - 1.0f;
  return f < 0.8f ? 1 : 0;
}
__device__ __forceinline__ ushort f2bf(float f) {
  uint32_t u = __float_as_uint(f);
  uint32_t r = (u + 0x7FFFu + ((u >> 16) & 1u)) >> 16;
  return (ushort)r;
}
__device__ __forceinline__ float bf2f(ushort u) {
  return __uint_as_float(((uint32_t)u) << 16);
}

// ---------------- byte masks: 0xFF = keep, 0x00 = drop --------------------
// m0B: [4][4096][128] (k>=100 -> 0) ; m1B: [4][4096][512]
__global__ __launch_bounds__(256) void masksB(uchar* __restrict__ m0B,
                                              uchar* __restrict__ m1B) {
  uint32_t k0a, k0b, k1a, k1b;
  tf2x32(0u, 42u, 0u, 0u, k0a, k0b);
  tf2x32(0u, 42u, 0u, 1u, k1a, k1b);
  const int T0 = 4 * BATCH * K0P;     // 2,097,152
  const int T1 = 4 * BATCH * UNITS;   // 8,388,608
  for (int i = blockIdx.x * blockDim.x + threadIdx.x; i < T0 + T1;
       i += gridDim.x * blockDim.x) {
    if (i < T0) {
      const int g = i >> 19, b = (i >> 7) & 4095, k = i & 127;
      uchar v = 0;
      if (k < EMB) {
        uint32_t y0, y1;
        tf2x32(k0a, k0b, 0u, (uint32_t)(g * (BATCH * EMB) + b * EMB + k), y0, y1);
        v = keepbit(y0 ^ y1) ? 0xFFu : 0u;
      }
      m0B[i] = v;
    } else {
      const int j = i - T0;
      const int g = j >> 21, b = (j >> 9) & 4095, k = j & 511;
      uint32_t y0, y1;
      tf2x32(k1a, k1b, 0u, (uint32_t)(g * (BATCH * UNITS) + b * UNITS + k), y0, y1);
      m1B[j] = keepbit(y0 ^ y1) ? 0xFFu : 0u;
    }
  }
}

// weight convert+transpose+scale: src[K][2048] f32 -> dst[2048][Kpad] bf16
__global__ __launch_bounds__(256) void convT(const float* __restrict__ src,
                                             ushort* __restrict__ dst,
                                             int Ksrc, int Kpad, float scale) {
  __shared__ float t[32][33];
  const int n0 = blockIdx.x * 32, kk0 = blockIdx.y * 32;
  const int tx = threadIdx.x & 31, ty = threadIdx.x >> 5;
#pragma unroll
  for (int r = ty; r < 32; r += 8) {
    const int k = kk0 + r;
    t[r][tx] = (k < Ksrc) ? src[(size_t)k * 2048 + n0 + tx] : 0.f;
  }
  __syncthreads();
#pragma unroll
  for (int r = ty; r < 32; r += 8)
    dst[(size_t)(n0 + r) * Kpad + kk0 + tx] = f2bf(scale * t[tx][r]);
}

// X[s][b][k] = bf16(embed[inputs[b,s], k]) (k<100), 0 pad — for s = 0,1,2
__global__ __launch_bounds__(256) void xprep3(const int* __restrict__ inputs,
                                              const float* __restrict__ embed,
                                              ushort* __restrict__ X0,
                                              ushort* __restrict__ X1,
                                              ushort* __restrict__ X2) {
  const int i = blockIdx.x * 256 + threadIdx.x;   // 3 * 65536 threads
  const int s = i >> 16, r = i & 65535;
  const int b = r >> 4, k = (r & 15) * 8;
  ushort* X = (s == 0) ? X0 : (s == 1) ? X1 : X2;
  const int idx = inputs[b * TT + s];
  ushort v[8];
#pragma unroll
  for (int j = 0; j < 8; j++) {
    const int kk = k + j;
    v[j] = (kk < EMB) ? f2bf(embed[(size_t)idx * EMB + kk]) : (ushort)0;
  }
  *(bf16x8*)(X + (size_t)b * K0P + k) = *(bf16x8*)v;
}

__device__ __forceinline__ void gload16(const void* g, void* l) {
  __builtin_amdgcn_global_load_lds(
      (const __attribute__((address_space(1))) unsigned int*)g,
      (__attribute__((address_space(3))) unsigned int*)l, 16, 0, 0);
}

// ---------------- one GEMM segment (K-loop) over acc ----------------------
// Block tile: 128 rows x [4 gates][64 h]. Waves 2x2: (wr: 64 rows, wc: 32 h).
// acc[fi][g*2+hf], col = g*64(+LDS) / g*512(+global h) + wc*32 + hf*16 + fr.
template <bool MASKED>
__device__ __forceinline__ void gemm_seg(
    const ushort* __restrict__ A, int K, const ushort* __restrict__ Bw,
    const uchar* __restrict__ mB, int bm0, int bh0, int tid,
    ushort* As, ushort* Bs, f32x4 acc[4][8]) {
  const int w = tid >> 6, l = tid & 63;
  const int wr = w >> 1, wc = w & 1;
  const int fr = l & 15, kq = l >> 4;
  const int srow = l >> 2, schunk = (l & 3) * 8;

#pragma unroll 1
  for (int k0 = 0; k0 < K; k0 += 32) {
    // A staging: 8 tiles x 16 rows; wave w stages tiles {w, w+4}
#pragma unroll
    for (int c2 = 0; c2 < 2; c2++) {
      const int rt = w + c2 * 4;
      gload16(A + (size_t)(bm0 + rt * 16 + srow) * K + k0 + schunk,
              As + rt * 512);
    }
    // B staging: 16 col-tiles; wave w stages tiles {4w..4w+3}
#pragma unroll
    for (int c2 = 0; c2 < 4; c2++) {
      const int ct = w * 4 + c2;
      const int col = ct * 16 + srow;             // 0..255
      const int nrow = (col >> 6) * 512 + bh0 + (col & 63);
      gload16(Bw + (size_t)nrow * K + k0 + schunk, Bs + ct * 512);
    }
    // mask bytes (per-lane, L2-resident)
    uint2 md[4][4];
    if (MASKED) {
#pragma unroll
      for (int fi = 0; fi < 4; fi++) {
        const int row = bm0 + wr * 64 + fi * 16 + fr;
#pragma unroll
        for (int g = 0; g < 4; g++)
          md[fi][g] = *(const uint2*)(mB + (size_t)(g * BATCH + row) * K + k0 +
                                      kq * 8);
      }
    }
    __syncthreads();

    u32x4 af[4];
    bf16x8 bf[8];
#pragma unroll
    for (int fi = 0; fi < 4; fi++)
      af[fi] = *(const u32x4*)&As[(wr * 64 + fi * 16 + fr) * 32 + kq * 8];
#pragma unroll
    for (int g = 0; g < 4; g++)
#pragma unroll
      for (int hf = 0; hf < 2; hf++)
        bf[g * 2 + hf] =
            *(const bf16x8*)&Bs[((g * 4 + wc * 2 + hf) * 16 + fr) * 32 + kq * 8];

#pragma unroll
    for (int g = 0; g < 4; g++) {
#pragma unroll
      for (int fi = 0; fi < 4; fi++) {
        u32x4 ua = af[fi];
        if (MASKED) {
          const uint2 m = md[fi][g];
          ua.x &= __builtin_amdgcn_perm(m.x, m.x, 0x01010000u);
          ua.y &= __builtin_amdgcn_perm(m.x, m.x, 0x03030202u);
          ua.z &= __builtin_amdgcn_perm(m.y, m.y, 0x01010000u);
          ua.w &= __builtin_amdgcn_perm(m.y, m.y, 0x03030202u);
        }
        const bf16x8 a = __builtin_bit_cast(bf16x8, ua);
        acc[fi][g * 2 + 0] = __builtin_amdgcn_mfma_f32_16x16x32_bf16(
            a, bf[g * 2 + 0], acc[fi][g * 2 + 0], 0, 0, 0);
        acc[fi][g * 2 + 1] = __builtin_amdgcn_mfma_f32_16x16x32_bf16(
            a, bf[g * 2 + 1], acc[fi][g * 2 + 1], 0, 0, 0);
      }
    }
    __syncthreads();
  }
}

// ---------------- fused step: l1(t) blocks + l0(t+1) blocks ---------------
__global__ __launch_bounds__(256, 2) void fused_step(
    int nl1,
    const ushort* __restrict__ h0b_cur, const ushort* __restrict__ h1b_prev,
    ushort* __restrict__ h1b_out, float* __restrict__ c1f,
    const ushort* __restrict__ W1T, const ushort* __restrict__ U1T,
    const float* __restrict__ b1, int nl0, const ushort* __restrict__ Xcur,
    ushort* __restrict__ h0b_out, float* __restrict__ c0f,
    const ushort* __restrict__ W0T, const ushort* __restrict__ U0T,
    const float* __restrict__ b0, const uchar* __restrict__ mask1B,
    const uchar* __restrict__ mask0B, int tprep, const int* __restrict__ inputs,
    const float* __restrict__ embed, ushort* __restrict__ Xprep) {
  __shared__ __align__(16) ushort smem[12288];  // As 4K + Bs 8K ushorts
  const int bid = blockIdx.x, tid = threadIdx.x;
  const bool isl1 = bid < nl1;
  const int lbid = isl1 ? bid : bid - nl1;
  const int cid = (lbid & 7) * 32 + (lbid >> 3);  // XCD-chunked
  const int bm0 = (cid >> 3) * 128;
  const int bh0 = (cid & 7) * 64;
  const int w = tid >> 6, l = tid & 63;
  const int wr = w >> 1, wc = w & 1;
  const int fr = l & 15, kq = l >> 4;

  const ushort *Amask, *Aun, *BW, *BU;
  const float* bias;
  const uchar* mB;
  float* cblob;
  ushort* hout;
  int Km;
  if (isl1) {
    Amask = h0b_cur; Km = UNITS; Aun = h1b_prev; BW = W1T; BU = U1T;
    bias = b1; mB = mask1B; cblob = c1f; hout = h1b_out;
  } else {
    Amask = Xcur; Km = K0P; Aun = h0b_cur; BW = W0T; BU = U0T;
    bias = b0; mB = mask0B; cblob = c0f; hout = h0b_out;
  }

  f32x4 acc[4][8] = {};
  ushort* As = smem;
  ushort* Bs = smem + 4096;

  gemm_seg<true>(Amask, Km, BW, mB, bm0, bh0, tid, As, Bs, acc);
  gemm_seg<false>(Aun, UNITS, BU, nullptr, bm0, bh0, tid, As, Bs, acc);

  // ---- epilogue: gates, c update (frag-layout blob), h via LDS transpose --
  float* cb = cblob + (size_t)cid * 8192 + tid * 32;
  f32x4 cold[8];
#pragma unroll
  for (int q = 0; q < 8; q++) cold[q] = *(const f32x4*)(cb + q * 4);

  float bi[2], bfv[2], bg[2], bo[2];
#pragma unroll
  for (int hf = 0; hf < 2; hf++) {
    const int h = bh0 + wc * 32 + hf * 16 + fr;
    bi[hf] = bias[h];
    bfv[hf] = bias[512 + h];
    bg[hf] = bias[1024 + h];
    bo[hf] = bias[1536 + h];
  }

  f32x4 cnew[8];
#pragma unroll
  for (int fi = 0; fi < 4; fi++) {
#pragma unroll
    for (int hf = 0; hf < 2; hf++) {
#pragma unroll
      for (int jj = 0; jj < 4; jj++) {
        const float zi = acc[fi][0 + hf][jj] + bi[hf];
        const float zf = acc[fi][2 + hf][jj] + bfv[hf];
        const float zg = acc[fi][4 + hf][jj] + bg[hf];
        const float zo = acc[fi][6 + hf][jj] + bo[hf];
        const float iv = 1.f / (1.f + __expf(-zi));
        const float fv = 1.f / (1.f + __expf(-zf));
        const float gv = tanhf(zg);
        const float ov = 1.f / (1.f + __expf(-zo));
        const float cn = fv * cold[fi * 2 + hf][jj] + iv * gv;
        cnew[fi * 2 + hf][jj] = cn;
        const float hn = ov * tanhf(cn);
        const int rloc = wr * 64 + fi * 16 + kq * 4 + jj;
        const int hloc = wc * 32 + hf * 16 + fr;
        smem[rloc * 64 + hloc] = f2bf(hn);
      }
    }
  }
#pragma unroll
  for (int q = 0; q < 8; q++) *(f32x4*)(cb + q * 4) = cnew[q];
  __syncthreads();

  // coalesced h writeback: 128 rows x 128B lines
#pragma unroll
  for (int c2 = 0; c2 < 4; c2++) {
    const int idx = c2 * 256 + tid;        // 1024 chunks of 8 ushorts
    const int rloc = idx >> 3, hcol = (idx & 7) * 8;
    *(bf16x8*)(hout + (size_t)(bm0 + rloc) * UNITS + bh0 + hcol) =
        *(const bf16x8*)&smem[rloc * 64 + hcol];
  }

  // X prep for step t+3 (l0 blocks only)
  if (!isl1 && tprep >= 0) {
    const int base = lbid * 2048 + tid * 8;  // over 4096*128
    const int b = base >> 7, k = base & 127;
    const int idx = inputs[b * TT + tprep];
    ushort v[8];
#pragma unroll
    for (int j = 0; j < 8; j++) {
      const int kk = k + j;
      v[j] = (kk < EMB) ? f2bf(embed[(size_t)idx * EMB + kk]) : (ushort)0;
    }
    *(bf16x8*)(Xprep + (size_t)b * K0P + k) = *(bf16x8*)v;
  }
}

// ---------------- final projection ---------------------------------------
__global__ __launch_bounds__(256) void out_kernel(const ushort* __restrict__ h1b,
                                                  const float* __restrict__ Wout,
                                                  const float* __restrict__ bout,
                                                  float* __restrict__ out) {
  const int wid = (blockIdx.x * blockDim.x + threadIdx.x) >> 6;
  const int lane = threadIdx.x & 63;
  if (wid >= BATCH) return;
  const ushort* hr = h1b + (size_t)wid * UNITS;
  float s = 0.f;
#pragma unroll
  for (int j = 0; j < UNITS; j += 64) s += bf2f(hr[j + lane]) * Wout[j + lane];
  for (int off = 32; off; off >>= 1) s += __shfl_down(s, off, 64);
  if (lane == 0) out[wid] = 1.f / (1.f + __expf(-(s + bout[0])));
}

// --------------------------------------------------------------------------
extern "C" void kernel_launch(void* const* d_in, const int* in_sizes, int n_in,
                              void* d_out, int out_size, void* d_ws, size_t ws_size,
                              hipStream_t stream) {
  const int* inputs = (const int*)d_in[0];
  const float* embed = (const float*)d_in[1];
  const float* W0 = (const float*)d_in[2];
  const float* U0 = (const float*)d_in[3];
  const float* b0 = (const float*)d_in[4];
  const float* W1 = (const float*)d_in[5];
  const float* U1 = (const float*)d_in[6];
  const float* b1 = (const float*)d_in[7];
  const float* Wout = (const float*)d_in[8];
  const float* bout = (const float*)d_in[9];
  float* out = (float*)d_out;

  char* ws = (char*)d_ws;
  const size_t MB = 1 << 20;
  float* c0f    = (float*)(ws);                  //  8 MB  (zero)
  float* c1f    = (float*)(ws + 8 * MB);         //  8 MB  (zero)
  ushort* h0b1  = (ushort*)(ws + 16 * MB);       //  4 MB  (zero)
  ushort* h1b1  = (ushort*)(ws + 20 * MB);       //  4 MB  (zero)
  ushort* h0b0  = (ushort*)(ws + 24 * MB);       //  4 MB
  ushort* h1b0  = (ushort*)(ws + 28 * MB);       //  4 MB
  ushort* X0    = (ushort*)(ws + 32 * MB);       //  1 MB
  ushort* X1    = (ushort*)(ws + 33 * MB);       //  1 MB
  ushort* X2    = (ushort*)(ws + 34 * MB);       //  1 MB
  ushort* W0T   = (ushort*)(ws + 35 * MB);       //  0.5 MB [2048][128]
  ushort* U0T   = (ushort*)(ws + 36 * MB);       //  2 MB   [2048][512]
  ushort* W1T   = (ushort*)(ws + 38 * MB);       //  2 MB
  ushort* U1T   = (ushort*)(ws + 40 * MB);       //  2 MB
  uchar* m0B    = (uchar*)(ws + 42 * MB);        //  2 MB   [4][4096][128]
  uchar* m1B    = (uchar*)(ws + 44 * MB);        //  8 MB   [4][4096][512]

  ushort* h0b[2] = {h0b0, h0b1};
  ushort* h1b[2] = {h1b0, h1b1};
  ushort* X[3] = {X0, X1, X2};

  hipMemsetAsync(ws, 0, 24 * MB, stream);          // c0f,c1f,h0b1,h1b1

  masksB<<<8192, 256, 0, stream>>>(m0B, m1B);
  {
    dim3 g0(2048 / 32, K0P / 32);
    convT<<<g0, 256, 0, stream>>>(W0, W0T, EMB, K0P, 1.25f);
    dim3 g1(2048 / 32, UNITS / 32);
    convT<<<g1, 256, 0, stream>>>(U0, U0T, UNITS, UNITS, 1.0f);
    convT<<<g1, 256, 0, stream>>>(W1, W1T, UNITS, UNITS, 1.25f);
    convT<<<g1, 256, 0, stream>>>(U1, U1T, UNITS, UNITS, 1.0f);
  }
  xprep3<<<768, 256, 0, stream>>>(inputs, embed, X0, X1, X2);

  // prologue: l0(t=0) only — reads X[0], h_prev = h0b[1] (zeros), writes h0b[0]
  fused_step<<<256, 256, 0, stream>>>(
      0, h0b[1], h1b[1], h1b[0], c1f, W1T, U1T, b1,
      256, X[0], h0b[0], c0f, W0T, U0T, b0, m1B, m0B,
      -1, inputs, embed, X[0]);

  for (int k = 0; k < TT; k++) {
    const int p = k & 1;
    const int nl0 = (k < TT - 1) ? 256 : 0;
    const int tprep = (k + 3 < TT) ? (k + 3) : -1;
    fused_step<<<256 + nl0, 256, 0, stream>>>(
        256, h0b[p], h1b[p ^ 1], h1b[p], c1f, W1T, U1T, b1,
        nl0, X[(k + 1) % 3], h0b[p ^ 1], c0f, W0T, U0T, b0, m1B, m0B,
        tprep, inputs, embed, X[k % 3]);
  }

  out_kernel<<<BATCH * 64 / 256, 256, 0, stream>>>(h1b[1], Wout, bout, out);
}